// Round 13
// baseline (237.318 us; speedup 1.0000x reference)
//
#include <hip/hip_runtime.h>
#include <stdint.h>

namespace {

typedef float v2f __attribute__((ext_vector_type(2)));
typedef int   v2i __attribute__((ext_vector_type(2)));

constexpr int H      = 32;    // LSTM_SIZE
constexpr int NEDGE  = 128;
constexpr float TINY   = 1.1754943508222875e-38f;  // finfo(f32).tiny
constexpr float L2E    = 1.4426950408889634f;      // log2(e)
constexpr float LN2    = 0.6931471805599453f;

__device__ __forceinline__ void tf_round(uint32_t& x0, uint32_t& x1, int r) {
  x0 += x1;
  x1 = (x1 << r) | (x1 >> (32 - r));
  x1 ^= x0;
}

// Threefry-2x32, 20 rounds — bit-exact JAX threefry2x32_p
__device__ __forceinline__ void tf2x32(uint32_t k0, uint32_t k1,
                                       uint32_t& x0, uint32_t& x1) {
  const uint32_t ks2 = k0 ^ k1 ^ 0x1BD11BDAu;
  x0 += k0; x1 += k1;
  tf_round(x0,x1,13); tf_round(x0,x1,15); tf_round(x0,x1,26); tf_round(x0,x1, 6);
  x0 += k1;  x1 += ks2 + 1u;
  tf_round(x0,x1,17); tf_round(x0,x1,29); tf_round(x0,x1,16); tf_round(x0,x1,24);
  x0 += ks2; x1 += k0 + 2u;
  tf_round(x0,x1,13); tf_round(x0,x1,15); tf_round(x0,x1,26); tf_round(x0,x1, 6);
  x0 += k0;  x1 += k1 + 3u;
  tf_round(x0,x1,17); tf_round(x0,x1,29); tf_round(x0,x1,16); tf_round(x0,x1,24);
  x0 += k1;  x1 += ks2 + 4u;
  tf_round(x0,x1,13); tf_round(x0,x1,15); tf_round(x0,x1,26); tf_round(x0,x1, 6);
  x0 += ks2; x1 += k0 + 5u;
}

// ---- native-instruction transcendentals
__device__ __forceinline__ float fexp(float x) {       // e^x
  return __builtin_amdgcn_exp2f(x * L2E);
}
__device__ __forceinline__ float flog(float x) {       // ln(x)
  return __builtin_amdgcn_logf(x) * LN2;
}
__device__ __forceinline__ float fsigmoid(float x) {   // 1/(1+e^-x)
  return __builtin_amdgcn_rcpf(1.0f + __builtin_amdgcn_exp2f(-x * L2E));
}
__device__ __forceinline__ float ftanh(float x) {
  const float ax = __builtin_fabsf(x);
  const float t  = __builtin_amdgcn_exp2f(ax * (-2.0f * L2E));  // e^(-2|x|)
  const float r  = (1.0f - t) * __builtin_amdgcn_rcpf(1.0f + t);
  return __builtin_copysignf(r, x);
}

__device__ __forceinline__ float rdlane(float v, int i) {
  return __int_as_float(__builtin_amdgcn_readlane(__float_as_int(v), i));
}

template <int CTRL>
__device__ __forceinline__ float dppf(float v) {
  return __int_as_float(__builtin_amdgcn_update_dpp(
      __float_as_int(v), __float_as_int(v), CTRL, 0xF, 0xF, false));
}

// 64-lane reductions: DPP butterfly within rows of 16, then 4 readlanes.
__device__ __forceinline__ float wave_sum64(float v) {
  v += dppf<0xB1>(v);
  v += dppf<0x4E>(v);
  v += dppf<0x141>(v);
  v += dppf<0x140>(v);
  return (rdlane(v, 15) + rdlane(v, 31)) + (rdlane(v, 47) + rdlane(v, 63));
}

__device__ __forceinline__ float wave_max64(float v) {
  v = fmaxf(v, dppf<0xB1>(v));
  v = fmaxf(v, dppf<0x4E>(v));
  v = fmaxf(v, dppf<0x141>(v));
  v = fmaxf(v, dppf<0x140>(v));
  return fmaxf(fmaxf(rdlane(v, 15), rdlane(v, 31)),
               fmaxf(rdlane(v, 47), rdlane(v, 63)));
}

__device__ __forceinline__ v2f pkfma(v2f a, v2f b, v2f c) {
  return __builtin_elementwise_fma(a, b, c);   // -> v_pk_fma_f32
}

// Cross-half swap (gfx950 VALU): r.x = g[lane&31] (i or g gate row),
// r.y = g[(lane&31)+32] (f or o gate row), identical in both halves.
__device__ __forceinline__ v2f permswap_pair(float g) {
  const v2i r = __builtin_amdgcn_permlane32_swap(
      __float_as_int(g), __float_as_int(g), false, false);
  return v2f{__int_as_float(r.x), __int_as_float(r.y)};
}

// 32-MAC dot of rdlane-broadcast hsrc against LDS weight row, 4 chains.
#define H_DOT(A0, A1, A2, A3, HSRC, WMAT, ROW)                             \
  _Pragma("unroll")                                                        \
  for (int q = 0; q < 8; ++q) {                                            \
    const float4 w = WMAT[q][ROW];                                         \
    A0 = fmaf(rdlane(HSRC, 4*q+0), w.x, A0);                               \
    A1 = fmaf(rdlane(HSRC, 4*q+1), w.y, A1);                               \
    A2 = fmaf(rdlane(HSRC, 4*q+2), w.z, A2);                               \
    A3 = fmaf(rdlane(HSRC, 4*q+3), w.w, A3);                               \
  }

__global__ __launch_bounds__(128, 1)
void ctrl_kernel(const float* __restrict__ input_vars,
                 const float* __restrict__ W_ih0, const float* __restrict__ W_hh0,
                 const float* __restrict__ b_ih0, const float* __restrict__ b_hh0,
                 const float* __restrict__ W_ih1, const float* __restrict__ W_hh1,
                 const float* __restrict__ b_ih1, const float* __restrict__ b_hh1,
                 const float* __restrict__ embd,
                 const float* __restrict__ W_pred, const float* __restrict__ b_pred,
                 float* __restrict__ out) {
  const int tid  = threadIdx.x;     // wave0: LSTM0 + PRNG; wave1: softmax; both: LSTM1+argmax
  const int lane = tid & 63;
  const int wid  = tid >> 6;
  const int rB   = lane + 64;

  __shared__ float4 Wl[4][8][128];                 // 64 KiB weights
  __shared__ __align__(16) float embd_lds[65 * H]; // row 64 = input_vars
  __shared__ __align__(16) float h0buf[2][H];      // dbuf by t&1
  __shared__ __align__(16) float gumbuf[2][64];    // dbuf by t&1
  __shared__ __align__(16) float arch_lds[NEDGE];

#define STAGE(MAT, SRC)                                                    \
  _Pragma("unroll")                                                        \
  for (int j = 0; j < 8; ++j) {                                            \
    const int i = tid + 128 * j;                                           \
    const int k4 = i & 7, row = i >> 3;                                    \
    Wl[MAT][k4][row] = reinterpret_cast<const float4*>(SRC)[row * 8 + k4]; \
  }
  STAGE(0, W_ih0)
  STAGE(1, W_hh0)
  STAGE(2, W_ih1)
  STAGE(3, W_hh1)
#undef STAGE
#pragma unroll
  for (int j = 0; j < 4; ++j)
    reinterpret_cast<float4*>(embd_lds)[tid + 128 * j] =
        reinterpret_cast<const float4*>(embd)[tid + 128 * j];
  if (tid < 8)
    reinterpret_cast<float4*>(&embd_lds[64 * H])[tid] =
        reinterpret_cast<const float4*>(input_vars)[tid];

  const float bsum0A = b_ih0[lane] + b_hh0[lane];
  const float bsum0B = b_ih0[rB]   + b_hh0[rB];
  const float bsum1A = b_ih1[lane] + b_hh1[lane];
  const float bsum1B = b_ih1[rB]   + b_hh1[rB];
  const float bp = b_pred[lane];
  float4 wp4[8];
#pragma unroll
  for (int q = 0; q < 8; ++q)
    wp4[q] = reinterpret_cast<const float4*>(W_pred + lane * H)[q];

  float c0 = 0.f, h0v = 0.f;          // wave0-private LSTM0 state
  float c1 = 0.f, h1v = 0.f;          // redundant on both waves
  int   xrow = 64;                    // wave0: current input row (SGPR)
  uint32_t k0 = 0u, k1 = 42u;         // key chain on wave0
  float lp_sum = 0.f, ent_sum = 0.f;  // wave1
  float logit_prev = 0.f;             // wave1: deferred softmax state
  int   idx_prev = 0;

  // ---- prologue: wave0 computes gum(0) (exact R12 threefry sequence)
  if (wid == 0) {
    uint32_t r0 = 0u, r1 = (uint32_t)(lane & 1);
    tf2x32(k0, k1, r0, r1);
    const uint32_t n0 = (uint32_t)__builtin_amdgcn_readlane((int)r0, 0);
    const uint32_t n1 = (uint32_t)__builtin_amdgcn_readlane((int)r1, 0);
    const uint32_t s0 = (uint32_t)__builtin_amdgcn_readlane((int)r0, 1);
    const uint32_t s1 = (uint32_t)__builtin_amdgcn_readlane((int)r1, 1);
    uint32_t x0 = 0u, x1 = (uint32_t)lane;
    tf2x32(s0, s1, x0, x1);
    const uint32_t bits = x0 ^ x1;
    k0 = n0; k1 = n1;
    float u = __uint_as_float(0x3f800000u | (bits >> 9)) - 1.0f;
    u = fmaxf(u + TINY, TINY);
    gumbuf[0][lane] = -flog(-flog(u));
  }
  __syncthreads();

  for (int t = 0; t < NEDGE; ++t) {
    // ======== phase1 ========
    // LSTM1 accumulators (both waves): hoisted h1(t-1) part via own-reg rdlane
    float rA0=0.f, rA1=0.f, rA2=0.f, rA3=0.f;
    float rB0=0.f, rB1=0.f, rB2=0.f, rB3=0.f;
    H_DOT(rA0, rA1, rA2, rA3, h1v, Wl[3], lane)
    H_DOT(rB0, rB1, rB2, rB3, h1v, Wl[3], rB)

    if (wid == 0) {
      // LSTM0(t): x = embd_lds[xrow] (uniform), h = rdlane(own h0v)
      v2f xA01={0.f,0.f}, xA23={0.f,0.f}, xB01={0.f,0.f}, xB23={0.f,0.f};
      float hA0=0.f,hA1=0.f,hA2=0.f,hA3=0.f;
      float hB0=0.f,hB1=0.f,hB2=0.f,hB3=0.f;
#pragma unroll
      for (int q = 0; q < 8; ++q) {
        const float4 x4 =
            *reinterpret_cast<const float4*>(&embd_lds[xrow * H + 4 * q]);
        const float4 wxA = Wl[0][q][lane];
        const float4 wxB = Wl[0][q][rB];
        xA01 = pkfma(v2f{x4.x, x4.y}, v2f{wxA.x, wxA.y}, xA01);
        xA23 = pkfma(v2f{x4.z, x4.w}, v2f{wxA.z, wxA.w}, xA23);
        xB01 = pkfma(v2f{x4.x, x4.y}, v2f{wxB.x, wxB.y}, xB01);
        xB23 = pkfma(v2f{x4.z, x4.w}, v2f{wxB.z, wxB.w}, xB23);
      }
      H_DOT(hA0, hA1, hA2, hA3, h0v, Wl[1], lane)
      H_DOT(hB0, hB1, hB2, hB3, h0v, Wl[1], rB)
      const float gA = bsum0A + ((xA01.x + xA01.y) + (xA23.x + xA23.y))
                              + ((hA0 + hA1) + (hA2 + hA3));
      const float gB = bsum0B + ((xB01.x + xB01.y) + (xB23.x + xB23.y))
                              + ((hB0 + hB1) + (hB2 + hB3));
      const v2f gif = permswap_pair(gA);   // .x = i, .y = f
      const v2f ggo = permswap_pair(gB);   // .x = g, .y = o
      c0 = fsigmoid(gif.y) * c0 + fsigmoid(gif.x) * ftanh(ggo.x);
      h0v = fsigmoid(ggo.y) * ftanh(c0);
      h0buf[t & 1][lane & 31] = h0v;       // 2 lanes/addr same data: free
    } else if (t > 0) {
      // deferred softmax stats for step t-1 (own-reg logit/idx)
      const float e  = fexp(logit_prev);
      const float E  = wave_sum64(e);
      const float ES = wave_sum64(e * logit_prev);
      const float lse = flog(E);
      const float li  = rdlane(logit_prev, idx_prev);
      lp_sum  += li - lse;
      ent_sum += lse - ES / E;
    }
    __syncthreads();   // single barrier: h0(t) + gum(t) visible

    // ======== phase2 (redundant on BOTH waves, bit-identical) ========
    // finish LSTM1: x-part = h0(t) from LDS (uniform float4 reads)
#pragma unroll
    for (int q = 0; q < 8; ++q) {
      const float4 h4 =
          *reinterpret_cast<const float4*>(&h0buf[t & 1][4 * q]);
      const float4 wA = Wl[2][q][lane];
      const float4 wB = Wl[2][q][rB];
      rA0 = fmaf(h4.x, wA.x, rA0);
      rA1 = fmaf(h4.y, wA.y, rA1);
      rA2 = fmaf(h4.z, wA.z, rA2);
      rA3 = fmaf(h4.w, wA.w, rA3);
      rB0 = fmaf(h4.x, wB.x, rB0);
      rB1 = fmaf(h4.y, wB.y, rB1);
      rB2 = fmaf(h4.z, wB.z, rB2);
      rB3 = fmaf(h4.w, wB.w, rB3);
    }
    const float gA1 = bsum1A + ((rA0 + rA1) + (rA2 + rA3));
    const float gB1 = bsum1B + ((rB0 + rB1) + (rB2 + rB3));
    const v2f gif1 = permswap_pair(gA1);
    const v2f ggo1 = permswap_pair(gB1);
    c1  = fsigmoid(gif1.y) * c1 + fsigmoid(gif1.x) * ftanh(ggo1.x);
    h1v = fsigmoid(ggo1.y) * ftanh(c1);

    // logits (lane = op index): rdlane(own h1v) against register W_pred
    float p0=0.f, p1=0.f, p2=0.f, p3=0.f;
#pragma unroll
    for (int q = 0; q < 8; ++q) {
      const float4 w = wp4[q];
      p0 = fmaf(rdlane(h1v, 4*q+0), w.x, p0);
      p1 = fmaf(rdlane(h1v, 4*q+1), w.y, p1);
      p2 = fmaf(rdlane(h1v, 4*q+2), w.z, p2);
      p3 = fmaf(rdlane(h1v, 4*q+3), w.w, p3);
    }
    const float pre   = bp + ((p0 + p1) + (p2 + p3));
    const float logit = 2.5f * ftanh(pre * 0.2f);   // TANH_CONST, 1/TEMP
    const float pert  = logit + gumbuf[t & 1][lane];

    // argmax via DPP-max + ballot (tie -> lowest index); both waves identical
    const float M = wave_max64(pert);
    const unsigned long long msk = __ballot(pert == M);
    const int idxu = __ffsll((long long)msk) - 1;

    if (wid == 0) {
      xrow = idxu;                       // next-step x row (register, no LDS)
      // threefry+gumbel for t+1 (off-chain; overlaps nothing critical)
      uint32_t r0 = 0u, r1 = (uint32_t)(lane & 1);
      tf2x32(k0, k1, r0, r1);
      const uint32_t n0 = (uint32_t)__builtin_amdgcn_readlane((int)r0, 0);
      const uint32_t n1 = (uint32_t)__builtin_amdgcn_readlane((int)r1, 0);
      const uint32_t s0 = (uint32_t)__builtin_amdgcn_readlane((int)r0, 1);
      const uint32_t s1 = (uint32_t)__builtin_amdgcn_readlane((int)r1, 1);
      uint32_t x0 = 0u, x1 = (uint32_t)lane;
      tf2x32(s0, s1, x0, x1);
      const uint32_t bits = x0 ^ x1;
      k0 = n0; k1 = n1;
      float u = __uint_as_float(0x3f800000u | (bits >> 9)) - 1.0f;
      u = fmaxf(u + TINY, TINY);
      gumbuf[(t + 1) & 1][lane] = -flog(-flog(u));
    } else {
      arch_lds[t] = (float)idxu;         // uniform addr+data write
      logit_prev = logit;                // softmax deferred to next phase1
      idx_prev   = idxu;
    }
  }

  if (wid == 1) {
    // final deferred softmax (t = 127)
    const float e  = fexp(logit_prev);
    const float E  = wave_sum64(e);
    const float ES = wave_sum64(e * logit_prev);
    const float lse = flog(E);
    const float li  = rdlane(logit_prev, idx_prev);
    lp_sum  += li - lse;
    ent_sum += lse - ES / E;

    out[2 + lane]      = arch_lds[lane];
    out[2 + 64 + lane] = arch_lds[64 + lane];
    if (lane == 0) { out[0] = lp_sum; out[1] = ent_sum; }
  }
}

}  // namespace

extern "C" void kernel_launch(void* const* d_in, const int* in_sizes, int n_in,
                              void* d_out, int out_size, void* d_ws, size_t ws_size,
                              hipStream_t stream) {
  (void)in_sizes; (void)n_in; (void)d_ws; (void)ws_size; (void)out_size;
  const float* input_vars = (const float*)d_in[0];
  const float* W_ih0 = (const float*)d_in[1];
  const float* W_hh0 = (const float*)d_in[2];
  const float* b_ih0 = (const float*)d_in[3];
  const float* b_hh0 = (const float*)d_in[4];
  const float* W_ih1 = (const float*)d_in[5];
  const float* W_hh1 = (const float*)d_in[6];
  const float* b_ih1 = (const float*)d_in[7];
  const float* b_hh1 = (const float*)d_in[8];
  const float* embd  = (const float*)d_in[9];
  const float* W_pred = (const float*)d_in[10];
  const float* b_pred = (const float*)d_in[11];
  float* out = (float*)d_out;

  hipLaunchKernelGGL(ctrl_kernel, dim3(1), dim3(128), 0, stream,
                     input_vars, W_ih0, W_hh0, b_ih0, b_hh0,
                     W_ih1, W_hh1, b_ih1, b_hh1,
                     embd, W_pred, b_pred, out);
}

// Round 14
// 174.298 us; speedup vs baseline: 1.3616x; 1.3616x over previous
//
#include <hip/hip_runtime.h>
#include <stdint.h>

namespace {

typedef float v2f __attribute__((ext_vector_type(2)));
typedef int   v2i __attribute__((ext_vector_type(2)));

constexpr int H      = 32;    // LSTM_SIZE
constexpr int NEDGE  = 128;
constexpr float TINY   = 1.1754943508222875e-38f;  // finfo(f32).tiny
constexpr float L2E    = 1.4426950408889634f;      // log2(e)
constexpr float LN2    = 0.6931471805599453f;

__device__ __forceinline__ void tf_round(uint32_t& x0, uint32_t& x1, int r) {
  x0 += x1;
  x1 = (x1 << r) | (x1 >> (32 - r));
  x1 ^= x0;
}

// Threefry-2x32, 20 rounds — bit-exact JAX threefry2x32_p
__device__ __forceinline__ void tf2x32(uint32_t k0, uint32_t k1,
                                       uint32_t& x0, uint32_t& x1) {
  const uint32_t ks2 = k0 ^ k1 ^ 0x1BD11BDAu;
  x0 += k0; x1 += k1;
  tf_round(x0,x1,13); tf_round(x0,x1,15); tf_round(x0,x1,26); tf_round(x0,x1, 6);
  x0 += k1;  x1 += ks2 + 1u;
  tf_round(x0,x1,17); tf_round(x0,x1,29); tf_round(x0,x1,16); tf_round(x0,x1,24);
  x0 += ks2; x1 += k0 + 2u;
  tf_round(x0,x1,13); tf_round(x0,x1,15); tf_round(x0,x1,26); tf_round(x0,x1, 6);
  x0 += k0;  x1 += k1 + 3u;
  tf_round(x0,x1,17); tf_round(x0,x1,29); tf_round(x0,x1,16); tf_round(x0,x1,24);
  x0 += k1;  x1 += ks2 + 4u;
  tf_round(x0,x1,13); tf_round(x0,x1,15); tf_round(x0,x1,26); tf_round(x0,x1, 6);
  x0 += ks2; x1 += k0 + 5u;
}

// ---- native-instruction transcendentals
__device__ __forceinline__ float fexp(float x) {       // e^x
  return __builtin_amdgcn_exp2f(x * L2E);
}
__device__ __forceinline__ float flog(float x) {       // ln(x)
  return __builtin_amdgcn_logf(x) * LN2;
}
__device__ __forceinline__ float fsigmoid(float x) {   // 1/(1+e^-x)
  return __builtin_amdgcn_rcpf(1.0f + __builtin_amdgcn_exp2f(-x * L2E));
}
__device__ __forceinline__ float ftanh(float x) {
  const float ax = __builtin_fabsf(x);
  const float t  = __builtin_amdgcn_exp2f(ax * (-2.0f * L2E));  // e^(-2|x|)
  const float r  = (1.0f - t) * __builtin_amdgcn_rcpf(1.0f + t);
  return __builtin_copysignf(r, x);
}

__device__ __forceinline__ float rdlane(float v, int i) {
  return __int_as_float(__builtin_amdgcn_readlane(__float_as_int(v), i));
}

template <int CTRL>
__device__ __forceinline__ float dppf(float v) {
  return __int_as_float(__builtin_amdgcn_update_dpp(
      __float_as_int(v), __float_as_int(v), CTRL, 0xF, 0xF, false));
}

// 64-lane reductions: DPP butterfly within rows of 16, then 4 readlanes.
__device__ __forceinline__ float wave_sum64(float v) {
  v += dppf<0xB1>(v);
  v += dppf<0x4E>(v);
  v += dppf<0x141>(v);
  v += dppf<0x140>(v);
  return (rdlane(v, 15) + rdlane(v, 31)) + (rdlane(v, 47) + rdlane(v, 63));
}

__device__ __forceinline__ float wave_max64(float v) {
  v = fmaxf(v, dppf<0xB1>(v));
  v = fmaxf(v, dppf<0x4E>(v));
  v = fmaxf(v, dppf<0x141>(v));
  v = fmaxf(v, dppf<0x140>(v));
  return fmaxf(fmaxf(rdlane(v, 15), rdlane(v, 31)),
               fmaxf(rdlane(v, 47), rdlane(v, 63)));
}

__device__ __forceinline__ v2f pkfma(v2f a, v2f b, v2f c) {
  return __builtin_elementwise_fma(a, b, c);   // -> v_pk_fma_f32
}

// Cross-half swap (gfx950 VALU): r.x = g[lane&31] (i or g gate row),
// r.y = g[(lane&31)+32] (f or o gate row), identical in both halves.
__device__ __forceinline__ v2f permswap_pair(float g) {
  const v2i r = __builtin_amdgcn_permlane32_swap(
      __float_as_int(g), __float_as_int(g), false, false);
  return v2f{__int_as_float(r.x), __int_as_float(r.y)};
}

// 32-MAC dot of rdlane-broadcast hsrc against LDS weight row, 4 chains.
#define H_DOT(A0, A1, A2, A3, HSRC, WMAT, ROW)                             \
  _Pragma("unroll")                                                        \
  for (int q = 0; q < 8; ++q) {                                            \
    const float4 w = WMAT[q][ROW];                                         \
    A0 = fmaf(rdlane(HSRC, 4*q+0), w.x, A0);                               \
    A1 = fmaf(rdlane(HSRC, 4*q+1), w.y, A1);                               \
    A2 = fmaf(rdlane(HSRC, 4*q+2), w.z, A2);                               \
    A3 = fmaf(rdlane(HSRC, 4*q+3), w.w, A3);                               \
  }

__global__ __launch_bounds__(128, 1)
void ctrl_kernel(const float* __restrict__ input_vars,
                 const float* __restrict__ W_ih0, const float* __restrict__ W_hh0,
                 const float* __restrict__ b_ih0, const float* __restrict__ b_hh0,
                 const float* __restrict__ W_ih1, const float* __restrict__ W_hh1,
                 const float* __restrict__ b_ih1, const float* __restrict__ b_hh1,
                 const float* __restrict__ embd,
                 const float* __restrict__ W_pred, const float* __restrict__ b_pred,
                 float* __restrict__ out) {
  const int tid  = threadIdx.x;  // wave0: LSTM0 + PRNG; wave1: LSTM1 + sample
  const int lane = tid & 63;
  const int wid  = tid >> 6;
  const int rB   = lane + 64;

  __shared__ float4 Wl[4][8][128];                 // 64 KiB weights
  __shared__ __align__(16) float embd_lds[64 * H]; // 8 KiB embedding table
  __shared__ __align__(16) float h0buf[2][H];      // w0 -> w1, dbuf by t&1
  __shared__ __align__(16) float gumbuf[2][64];    // w0 -> w1, dbuf by t&1
  __shared__ __align__(16) float xbuf[2][H];       // w1 -> w0 (x row), dbuf
  __shared__ __align__(16) float arch_lds[NEDGE];

#define STAGE(MAT, SRC)                                                    \
  _Pragma("unroll")                                                        \
  for (int j = 0; j < 8; ++j) {                                            \
    const int i = tid + 128 * j;                                           \
    const int k4 = i & 7, row = i >> 3;                                    \
    Wl[MAT][k4][row] = reinterpret_cast<const float4*>(SRC)[row * 8 + k4]; \
  }
  STAGE(0, W_ih0)
  STAGE(1, W_hh0)
  STAGE(2, W_ih1)
  STAGE(3, W_hh1)
#undef STAGE
#pragma unroll
  for (int j = 0; j < 4; ++j)
    reinterpret_cast<float4*>(embd_lds)[tid + 128 * j] =
        reinterpret_cast<const float4*>(embd)[tid + 128 * j];
  if (tid < 8)
    reinterpret_cast<float4*>(&xbuf[0][0])[tid] =
        reinterpret_cast<const float4*>(input_vars)[tid];  // x(0) = input_vars

  const float bsum0A = b_ih0[lane] + b_hh0[lane];
  const float bsum0B = b_ih0[rB]   + b_hh0[rB];
  const float bsum1A = b_ih1[lane] + b_hh1[lane];
  const float bsum1B = b_ih1[rB]   + b_hh1[rB];
  const float bp = b_pred[lane];
  float4 wp4[8];                    // wave1 only
#pragma unroll
  for (int q = 0; q < 8; ++q)
    wp4[q] = reinterpret_cast<const float4*>(W_pred + lane * H)[q];

  float c0 = 0.f, h0v = 0.f;          // wave0 LSTM0 state
  float c1 = 0.f, h1v = 0.f;          // wave1 LSTM1 state
  uint32_t k0 = 0u, k1 = 42u;         // key chain on wave0
  float lp_sum = 0.f, ent_sum = 0.f;  // wave1
  float logit_prev = 0.f;             // wave1 deferred-softmax state
  int   idx_prev = 0;

  // ---- prologue: wave0 computes gum(0) (exact R12 threefry sequence)
  if (wid == 0) {
    uint32_t r0 = 0u, r1 = (uint32_t)(lane & 1);
    tf2x32(k0, k1, r0, r1);
    const uint32_t n0 = (uint32_t)__builtin_amdgcn_readlane((int)r0, 0);
    const uint32_t n1 = (uint32_t)__builtin_amdgcn_readlane((int)r1, 0);
    const uint32_t s0 = (uint32_t)__builtin_amdgcn_readlane((int)r0, 1);
    const uint32_t s1 = (uint32_t)__builtin_amdgcn_readlane((int)r1, 1);
    uint32_t x0 = 0u, x1 = (uint32_t)lane;
    tf2x32(s0, s1, x0, x1);
    const uint32_t bits = x0 ^ x1;
    k0 = n0; k1 = n1;
    float u = __uint_as_float(0x3f800000u | (bits >> 9)) - 1.0f;
    u = fmaxf(u + TINY, TINY);
    gumbuf[0][lane] = -flog(-flog(u));
  }
  __syncthreads();

  for (int t = 0; t < NEDGE; ++t) {
    // ======== phase1 ========
    // wave1's LSTM1 accumulators (carried across barrier M in registers)
    float rA0=0.f, rA1=0.f, rA2=0.f, rA3=0.f;
    float rB0=0.f, rB1=0.f, rB2=0.f, rB3=0.f;

    if (wid == 0) {
      // LSTM0(t): x = xbuf[t&1] (uniform LDS), h = rdlane(own h0v)
      v2f xA01={0.f,0.f}, xA23={0.f,0.f}, xB01={0.f,0.f}, xB23={0.f,0.f};
      float hA0=0.f,hA1=0.f,hA2=0.f,hA3=0.f;
      float hB0=0.f,hB1=0.f,hB2=0.f,hB3=0.f;
#pragma unroll
      for (int q = 0; q < 8; ++q) {
        const float4 x4 =
            *reinterpret_cast<const float4*>(&xbuf[t & 1][4 * q]);
        const float4 wxA = Wl[0][q][lane];
        const float4 wxB = Wl[0][q][rB];
        xA01 = pkfma(v2f{x4.x, x4.y}, v2f{wxA.x, wxA.y}, xA01);
        xA23 = pkfma(v2f{x4.z, x4.w}, v2f{wxA.z, wxA.w}, xA23);
        xB01 = pkfma(v2f{x4.x, x4.y}, v2f{wxB.x, wxB.y}, xB01);
        xB23 = pkfma(v2f{x4.z, x4.w}, v2f{wxB.z, wxB.w}, xB23);
      }
      H_DOT(hA0, hA1, hA2, hA3, h0v, Wl[1], lane)
      H_DOT(hB0, hB1, hB2, hB3, h0v, Wl[1], rB)
      const float gA = bsum0A + ((xA01.x + xA01.y) + (xA23.x + xA23.y))
                              + ((hA0 + hA1) + (hA2 + hA3));
      const float gB = bsum0B + ((xB01.x + xB01.y) + (xB23.x + xB23.y))
                              + ((hB0 + hB1) + (hB2 + hB3));
      const v2f gif = permswap_pair(gA);   // .x = i, .y = f
      const v2f ggo = permswap_pair(gB);   // .x = g, .y = o
      c0 = fsigmoid(gif.y) * c0 + fsigmoid(gif.x) * ftanh(ggo.x);
      h0v = fsigmoid(ggo.y) * ftanh(c0);
      h0buf[t & 1][lane & 31] = h0v;       // 2 lanes/addr same data: free
    } else {
      // hoisted LSTM1 h1(t-1)-partial via own-register rdlane (no LDS)
      H_DOT(rA0, rA1, rA2, rA3, h1v, Wl[3], lane)
      H_DOT(rB0, rB1, rB2, rB3, h1v, Wl[3], rB)
      if (t > 0) {
        // deferred softmax stats for step t-1 (own-reg logit/idx; no LDS)
        const float e  = fexp(logit_prev);
        const float E  = wave_sum64(e);
        const float ES = wave_sum64(e * logit_prev);
        const float lse = flog(E);
        const float li  = rdlane(logit_prev, idx_prev);
        lp_sum  += li - lse;
        ent_sum += lse - ES / E;
      }
    }
    __syncthreads();   // M: h0(t) visible to wave1

    // ======== phase2 ========
    if (wid == 0) {
      // threefry+gumbel for t+1 (overlaps wave1's LSTM1+sample)
      uint32_t r0 = 0u, r1 = (uint32_t)(lane & 1);
      tf2x32(k0, k1, r0, r1);
      const uint32_t n0 = (uint32_t)__builtin_amdgcn_readlane((int)r0, 0);
      const uint32_t n1 = (uint32_t)__builtin_amdgcn_readlane((int)r1, 0);
      const uint32_t s0 = (uint32_t)__builtin_amdgcn_readlane((int)r0, 1);
      const uint32_t s1 = (uint32_t)__builtin_amdgcn_readlane((int)r1, 1);
      uint32_t x0 = 0u, x1 = (uint32_t)lane;
      tf2x32(s0, s1, x0, x1);
      const uint32_t bits = x0 ^ x1;
      k0 = n0; k1 = n1;
      float u = __uint_as_float(0x3f800000u | (bits >> 9)) - 1.0f;
      u = fmaxf(u + TINY, TINY);
      gumbuf[(t + 1) & 1][lane] = -flog(-flog(u));
    } else {
      // finish LSTM1: x-part = h0(t) from LDS (uniform float4 reads)
#pragma unroll
      for (int q = 0; q < 8; ++q) {
        const float4 h4 =
            *reinterpret_cast<const float4*>(&h0buf[t & 1][4 * q]);
        const float4 wA = Wl[2][q][lane];
        const float4 wB = Wl[2][q][rB];
        rA0 = fmaf(h4.x, wA.x, rA0);
        rA1 = fmaf(h4.y, wA.y, rA1);
        rA2 = fmaf(h4.z, wA.z, rA2);
        rA3 = fmaf(h4.w, wA.w, rA3);
        rB0 = fmaf(h4.x, wB.x, rB0);
        rB1 = fmaf(h4.y, wB.y, rB1);
        rB2 = fmaf(h4.z, wB.z, rB2);
        rB3 = fmaf(h4.w, wB.w, rB3);
      }
      const float gA1 = bsum1A + ((rA0 + rA1) + (rA2 + rA3));
      const float gB1 = bsum1B + ((rB0 + rB1) + (rB2 + rB3));
      const v2f gif1 = permswap_pair(gA1);
      const v2f ggo1 = permswap_pair(gB1);
      c1  = fsigmoid(gif1.y) * c1 + fsigmoid(gif1.x) * ftanh(ggo1.x);
      h1v = fsigmoid(ggo1.y) * ftanh(c1);

      // logits (lane = op index): rdlane(own h1v) against register W_pred
      float p0=0.f, p1=0.f, p2=0.f, p3=0.f;
#pragma unroll
      for (int q = 0; q < 8; ++q) {
        const float4 w = wp4[q];
        p0 = fmaf(rdlane(h1v, 4*q+0), w.x, p0);
        p1 = fmaf(rdlane(h1v, 4*q+1), w.y, p1);
        p2 = fmaf(rdlane(h1v, 4*q+2), w.z, p2);
        p3 = fmaf(rdlane(h1v, 4*q+3), w.w, p3);
      }
      const float pre   = bp + ((p0 + p1) + (p2 + p3));
      const float logit = 2.5f * ftanh(pre * 0.2f);   // TANH_CONST, 1/TEMP
      const float pert  = logit + gumbuf[t & 1][lane];

      // argmax via DPP-max + ballot (tie -> lowest index)
      const float M = wave_max64(pert);
      const unsigned long long msk = __ballot(pert == M);
      const int idxu = __ffsll((long long)msk) - 1;

      arch_lds[t] = (float)idxu;          // uniform addr+data write
      logit_prev = logit;                 // softmax deferred to next phase1
      idx_prev   = idxu;
      // hand next-step x row to wave0 (bit copy; consecutive banks, free)
      xbuf[(t + 1) & 1][lane & 31] = embd_lds[idxu * H + (lane & 31)];
    }
    __syncthreads();                      // E: xbuf(t+1), gum(t+1) visible
  }

  if (wid == 1) {
    // final deferred softmax (t = 127)
    const float e  = fexp(logit_prev);
    const float E  = wave_sum64(e);
    const float ES = wave_sum64(e * logit_prev);
    const float lse = flog(E);
    const float li  = rdlane(logit_prev, idx_prev);
    lp_sum  += li - lse;
    ent_sum += lse - ES / E;

    out[2 + lane]      = arch_lds[lane];
    out[2 + 64 + lane] = arch_lds[64 + lane];
    if (lane == 0) { out[0] = lp_sum; out[1] = ent_sum; }
  }
}

}  // namespace

extern "C" void kernel_launch(void* const* d_in, const int* in_sizes, int n_in,
                              void* d_out, int out_size, void* d_ws, size_t ws_size,
                              hipStream_t stream) {
  (void)in_sizes; (void)n_in; (void)d_ws; (void)ws_size; (void)out_size;
  const float* input_vars = (const float*)d_in[0];
  const float* W_ih0 = (const float*)d_in[1];
  const float* W_hh0 = (const float*)d_in[2];
  const float* b_ih0 = (const float*)d_in[3];
  const float* b_hh0 = (const float*)d_in[4];
  const float* W_ih1 = (const float*)d_in[5];
  const float* W_hh1 = (const float*)d_in[6];
  const float* b_ih1 = (const float*)d_in[7];
  const float* b_hh1 = (const float*)d_in[8];
  const float* embd  = (const float*)d_in[9];
  const float* W_pred = (const float*)d_in[10];
  const float* b_pred = (const float*)d_in[11];
  float* out = (float*)d_out;

  hipLaunchKernelGGL(ctrl_kernel, dim3(1), dim3(128), 0, stream,
                     input_vars, W_ih0, W_hh0, b_ih0, b_hh0,
                     W_ih1, W_hh1, b_ih1, b_hh1,
                     embd, W_pred, b_pred, out);
}

// Round 15
// 140.444 us; speedup vs baseline: 1.6898x; 1.2411x over previous
//
#include <hip/hip_runtime.h>
#include <stdint.h>

namespace {

typedef float v2f __attribute__((ext_vector_type(2)));
typedef int   v2i __attribute__((ext_vector_type(2)));

constexpr int H      = 32;    // LSTM_SIZE
constexpr int NEDGE  = 128;
constexpr float TINY   = 1.1754943508222875e-38f;  // finfo(f32).tiny
constexpr float L2E    = 1.4426950408889634f;      // log2(e)
constexpr float LN2    = 0.6931471805599453f;

__device__ __forceinline__ void tf_round(uint32_t& x0, uint32_t& x1, int r) {
  x0 += x1;
  x1 = (x1 << r) | (x1 >> (32 - r));
  x1 ^= x0;
}

// Threefry-2x32, 20 rounds — bit-exact JAX threefry2x32_p
__device__ __forceinline__ void tf2x32(uint32_t k0, uint32_t k1,
                                       uint32_t& x0, uint32_t& x1) {
  const uint32_t ks2 = k0 ^ k1 ^ 0x1BD11BDAu;
  x0 += k0; x1 += k1;
  tf_round(x0,x1,13); tf_round(x0,x1,15); tf_round(x0,x1,26); tf_round(x0,x1, 6);
  x0 += k1;  x1 += ks2 + 1u;
  tf_round(x0,x1,17); tf_round(x0,x1,29); tf_round(x0,x1,16); tf_round(x0,x1,24);
  x0 += ks2; x1 += k0 + 2u;
  tf_round(x0,x1,13); tf_round(x0,x1,15); tf_round(x0,x1,26); tf_round(x0,x1, 6);
  x0 += k0;  x1 += k1 + 3u;
  tf_round(x0,x1,17); tf_round(x0,x1,29); tf_round(x0,x1,16); tf_round(x0,x1,24);
  x0 += k1;  x1 += ks2 + 4u;
  tf_round(x0,x1,13); tf_round(x0,x1,15); tf_round(x0,x1,26); tf_round(x0,x1, 6);
  x0 += ks2; x1 += k0 + 5u;
}

// ---- native-instruction transcendentals
__device__ __forceinline__ float fexp(float x) {       // e^x
  return __builtin_amdgcn_exp2f(x * L2E);
}
__device__ __forceinline__ float flog(float x) {       // ln(x)
  return __builtin_amdgcn_logf(x) * LN2;
}
__device__ __forceinline__ float fsigmoid(float x) {   // 1/(1+e^-x)
  return __builtin_amdgcn_rcpf(1.0f + __builtin_amdgcn_exp2f(-x * L2E));
}
__device__ __forceinline__ float ftanh(float x) {
  const float ax = __builtin_fabsf(x);
  const float t  = __builtin_amdgcn_exp2f(ax * (-2.0f * L2E));  // e^(-2|x|)
  const float r  = (1.0f - t) * __builtin_amdgcn_rcpf(1.0f + t);
  return __builtin_copysignf(r, x);
}

__device__ __forceinline__ float rdlane(float v, int i) {
  return __int_as_float(__builtin_amdgcn_readlane(__float_as_int(v), i));
}

template <int CTRL>
__device__ __forceinline__ float dppf(float v) {
  return __int_as_float(__builtin_amdgcn_update_dpp(
      __float_as_int(v), __float_as_int(v), CTRL, 0xF, 0xF, false));
}

// 64-lane reductions: DPP butterfly within rows of 16, then 4 readlanes.
__device__ __forceinline__ float wave_sum64(float v) {
  v += dppf<0xB1>(v);
  v += dppf<0x4E>(v);
  v += dppf<0x141>(v);
  v += dppf<0x140>(v);
  return (rdlane(v, 15) + rdlane(v, 31)) + (rdlane(v, 47) + rdlane(v, 63));
}

__device__ __forceinline__ float wave_max64(float v) {
  v = fmaxf(v, dppf<0xB1>(v));
  v = fmaxf(v, dppf<0x4E>(v));
  v = fmaxf(v, dppf<0x141>(v));
  v = fmaxf(v, dppf<0x140>(v));
  return fmaxf(fmaxf(rdlane(v, 15), rdlane(v, 31)),
               fmaxf(rdlane(v, 47), rdlane(v, 63)));
}

__device__ __forceinline__ v2f pkfma(v2f a, v2f b, v2f c) {
  return __builtin_elementwise_fma(a, b, c);   // -> v_pk_fma_f32
}

// Cross-half swap (gfx950 VALU): r.x = g[lane&31] (i or g gate row),
// r.y = g[(lane&31)+32] (f or o gate row), identical in both halves.
__device__ __forceinline__ v2f permswap_pair(float g) {
  const v2i r = __builtin_amdgcn_permlane32_swap(
      __float_as_int(g), __float_as_int(g), false, false);
  return v2f{__int_as_float(r.x), __int_as_float(r.y)};
}

__global__ __launch_bounds__(128, 1)
void ctrl_kernel(const float* __restrict__ input_vars,
                 const float* __restrict__ W_ih0, const float* __restrict__ W_hh0,
                 const float* __restrict__ b_ih0, const float* __restrict__ b_hh0,
                 const float* __restrict__ W_ih1, const float* __restrict__ W_hh1,
                 const float* __restrict__ b_ih1, const float* __restrict__ b_hh1,
                 const float* __restrict__ embd,
                 const float* __restrict__ W_pred, const float* __restrict__ b_pred,
                 float* __restrict__ out) {
  const int tid  = threadIdx.x;  // wave0: LSTM0 + PRNG; wave1: LSTM1 + sample
  const int lane = tid & 63;
  const int wid  = tid >> 6;
  const int rB   = lane + 64;

  __shared__ float4 Wh[2][8][128];                 // W_hh0, W_hh1 (32 KiB)
  __shared__ __align__(16) float embd_lds[64 * H]; // 8 KiB
  __shared__ __align__(16) float h0buf[2][H];      // w0 -> w1, dbuf by t&1
  __shared__ __align__(16) float gumbuf[2][64];    // w0 -> w1, dbuf by t&1
  __shared__ __align__(16) float xbuf[2][H];       // w1 -> w0, dbuf by t&1
  __shared__ __align__(16) float arch_lds[NEDGE];

#define STAGE(MAT, SRC)                                                    \
  _Pragma("unroll")                                                        \
  for (int j = 0; j < 8; ++j) {                                            \
    const int i = tid + 128 * j;                                           \
    const int k4 = i & 7, row = i >> 3;                                    \
    Wh[MAT][k4][row] = reinterpret_cast<const float4*>(SRC)[row * 8 + k4]; \
  }
  STAGE(0, W_hh0)
  STAGE(1, W_hh1)
#undef STAGE
#pragma unroll
  for (int j = 0; j < 4; ++j)
    reinterpret_cast<float4*>(embd_lds)[tid + 128 * j] =
        reinterpret_cast<const float4*>(embd)[tid + 128 * j];
  if (tid < 8)
    reinterpret_cast<float4*>(&xbuf[0][0])[tid] =
        reinterpret_cast<const float4*>(input_vars)[tid];  // x(0) = input_vars

  // Chain-leg input weights in REGISTERS: wave0 holds W_ih0 rows, wave1 W_ih1.
  const float* WX = (wid == 0) ? W_ih0 : W_ih1;
  float4 wxA[8], wxB[8];
#pragma unroll
  for (int q = 0; q < 8; ++q) {
    wxA[q] = reinterpret_cast<const float4*>(WX + lane * H)[q];
    wxB[q] = reinterpret_cast<const float4*>(WX + rB * H)[q];
  }
  const float bsum0A = b_ih0[lane] + b_hh0[lane];
  const float bsum0B = b_ih0[rB]   + b_hh0[rB];
  const float bsum1A = b_ih1[lane] + b_hh1[lane];
  const float bsum1B = b_ih1[rB]   + b_hh1[rB];
  const float bp = b_pred[lane];
  float4 wp4[8];
#pragma unroll
  for (int q = 0; q < 8; ++q)
    wp4[q] = reinterpret_cast<const float4*>(W_pred + lane * H)[q];

  float c0 = 0.f, h0v = 0.f;           // wave0 LSTM0 state
  float c1 = 0.f, h1v = 0.f;           // wave1 LSTM1 state
  // wave0 hoisted h0-dot accumulators (phase2(t-1) -> phase1(t)); h0(-1)=0
  v2f hoA01={0.f,0.f}, hoA23={0.f,0.f}, hoB01={0.f,0.f}, hoB23={0.f,0.f};
  uint32_t k0 = 0u, k1 = 42u;          // key chain (wave0)
  uint32_t s0c = 0u, s1c = 0u;         // subkey carried phase1 -> phase2
  float lp_sum = 0.f, ent_sum = 0.f;   // wave1
  float logit_prev = 0.f;
  int   idx_prev = 0;

  if (wid == 0) {
    // prologue: cipher1(key_0) -> key_1, sub_0; cipher2(sub_0) -> gum(0)
    uint32_t r0 = 0u, r1 = (uint32_t)(lane & 1);
    tf2x32(k0, k1, r0, r1);
    const uint32_t n0 = (uint32_t)__builtin_amdgcn_readlane((int)r0, 0);
    const uint32_t n1 = (uint32_t)__builtin_amdgcn_readlane((int)r1, 0);
    const uint32_t s0 = (uint32_t)__builtin_amdgcn_readlane((int)r0, 1);
    const uint32_t s1 = (uint32_t)__builtin_amdgcn_readlane((int)r1, 1);
    uint32_t x0 = 0u, x1 = (uint32_t)lane;
    tf2x32(s0, s1, x0, x1);
    const uint32_t bits = x0 ^ x1;
    k0 = n0; k1 = n1;
    float u = __uint_as_float(0x3f800000u | (bits >> 9)) - 1.0f;
    u = fmaxf(u + TINY, TINY);
    gumbuf[0][lane] = -flog(-flog(u));
  }
  __syncthreads();

  for (int t = 0; t < NEDGE; ++t) {
    // wave1 LSTM1 accumulators (phase1 hoisted -> phase2 finish)
    v2f rA01={0.f,0.f}, rA23={0.f,0.f}, rB01={0.f,0.f}, rB23={0.f,0.f};

    // ======== phase1 ========
    if (wid == 0) {
      // finish LSTM0(t): x-dot (register weights, uniform xbuf) + hoisted h-dot
      v2f xA01={0.f,0.f}, xA23={0.f,0.f}, xB01={0.f,0.f}, xB23={0.f,0.f};
#pragma unroll
      for (int q = 0; q < 8; ++q) {
        const float4 x4 =
            *reinterpret_cast<const float4*>(&xbuf[t & 1][4 * q]);
        xA01 = pkfma(v2f{x4.x, x4.y}, v2f{wxA[q].x, wxA[q].y}, xA01);
        xA23 = pkfma(v2f{x4.z, x4.w}, v2f{wxA[q].z, wxA[q].w}, xA23);
        xB01 = pkfma(v2f{x4.x, x4.y}, v2f{wxB[q].x, wxB[q].y}, xB01);
        xB23 = pkfma(v2f{x4.z, x4.w}, v2f{wxB[q].z, wxB[q].w}, xB23);
      }
      const float gA = bsum0A + ((xA01.x + xA01.y) + (xA23.x + xA23.y))
                              + ((hoA01.x + hoA01.y) + (hoA23.x + hoA23.y));
      const float gB = bsum0B + ((xB01.x + xB01.y) + (xB23.x + xB23.y))
                              + ((hoB01.x + hoB01.y) + (hoB23.x + hoB23.y));
      const v2f gif = permswap_pair(gA);   // .x = i, .y = f
      const v2f ggo = permswap_pair(gB);   // .x = g, .y = o
      c0 = fsigmoid(gif.y) * c0 + fsigmoid(gif.x) * ftanh(ggo.x);
      h0v = fsigmoid(ggo.y) * ftanh(c0);
      h0buf[t & 1][lane & 31] = h0v;       // 2 lanes/addr same data: free
      // cipher1 for step t+1: key_{t+1} -> (key_{t+2}, sub_{t+1})
      uint32_t r0 = 0u, r1 = (uint32_t)(lane & 1);
      tf2x32(k0, k1, r0, r1);
      k0  = (uint32_t)__builtin_amdgcn_readlane((int)r0, 0);
      k1  = (uint32_t)__builtin_amdgcn_readlane((int)r1, 0);
      s0c = (uint32_t)__builtin_amdgcn_readlane((int)r0, 1);
      s1c = (uint32_t)__builtin_amdgcn_readlane((int)r1, 1);
    } else {
      // hoisted LSTM1 h1(t-1)-dot via rdlane pairs against LDS W_hh1
#pragma unroll
      for (int q = 0; q < 8; ++q) {
        const float4 wA = Wh[1][q][lane];
        const float4 wB = Wh[1][q][rB];
        const v2f h01 = {rdlane(h1v, 4*q+0), rdlane(h1v, 4*q+1)};
        const v2f h23 = {rdlane(h1v, 4*q+2), rdlane(h1v, 4*q+3)};
        rA01 = pkfma(h01, v2f{wA.x, wA.y}, rA01);
        rA23 = pkfma(h23, v2f{wA.z, wA.w}, rA23);
        rB01 = pkfma(h01, v2f{wB.x, wB.y}, rB01);
        rB23 = pkfma(h23, v2f{wB.z, wB.w}, rB23);
      }
      if (t > 0) {
        // deferred softmax stats for step t-1
        const float e  = fexp(logit_prev);
        const float E  = wave_sum64(e);
        const float ES = wave_sum64(e * logit_prev);
        const float lse = flog(E);
        const float li  = rdlane(logit_prev, idx_prev);
        lp_sum  += li - lse;
        ent_sum += lse - ES / E;
      }
    }
    __syncthreads();   // M: h0(t) visible to wave1

    // ======== phase2 ========
    if (wid == 0) {
      // cipher2(sub_{t+1}) -> gum(t+1)
      uint32_t x0 = 0u, x1 = (uint32_t)lane;
      tf2x32(s0c, s1c, x0, x1);
      const uint32_t bits = x0 ^ x1;
      float u = __uint_as_float(0x3f800000u | (bits >> 9)) - 1.0f;
      u = fmaxf(u + TINY, TINY);
      gumbuf[(t + 1) & 1][lane] = -flog(-flog(u));
      // hoisted LSTM0 h0(t)-dot for step t+1 (own registers, LDS W_hh0)
      hoA01 = v2f{0.f,0.f}; hoA23 = v2f{0.f,0.f};
      hoB01 = v2f{0.f,0.f}; hoB23 = v2f{0.f,0.f};
#pragma unroll
      for (int q = 0; q < 8; ++q) {
        const float4 wA = Wh[0][q][lane];
        const float4 wB = Wh[0][q][rB];
        const v2f h01 = {rdlane(h0v, 4*q+0), rdlane(h0v, 4*q+1)};
        const v2f h23 = {rdlane(h0v, 4*q+2), rdlane(h0v, 4*q+3)};
        hoA01 = pkfma(h01, v2f{wA.x, wA.y}, hoA01);
        hoA23 = pkfma(h23, v2f{wA.z, wA.w}, hoA23);
        hoB01 = pkfma(h01, v2f{wB.x, wB.y}, hoB01);
        hoB23 = pkfma(h23, v2f{wB.z, wB.w}, hoB23);
      }
    } else {
      // finish LSTM1(t): x-part = h0(t) uniform reads x register W_ih1 rows
#pragma unroll
      for (int q = 0; q < 8; ++q) {
        const float4 h4 =
            *reinterpret_cast<const float4*>(&h0buf[t & 1][4 * q]);
        rA01 = pkfma(v2f{h4.x, h4.y}, v2f{wxA[q].x, wxA[q].y}, rA01);
        rA23 = pkfma(v2f{h4.z, h4.w}, v2f{wxA[q].z, wxA[q].w}, rA23);
        rB01 = pkfma(v2f{h4.x, h4.y}, v2f{wxB[q].x, wxB[q].y}, rB01);
        rB23 = pkfma(v2f{h4.z, h4.w}, v2f{wxB[q].z, wxB[q].w}, rB23);
      }
      const float gA1 = bsum1A + ((rA01.x + rA01.y) + (rA23.x + rA23.y));
      const float gB1 = bsum1B + ((rB01.x + rB01.y) + (rB23.x + rB23.y));
      const v2f gif1 = permswap_pair(gA1);
      const v2f ggo1 = permswap_pair(gB1);
      c1  = fsigmoid(gif1.y) * c1 + fsigmoid(gif1.x) * ftanh(ggo1.x);
      h1v = fsigmoid(ggo1.y) * ftanh(c1);

      // logits (lane = op index), pkfma-packed
      v2f p01 = {0.f, 0.f}, p23 = {0.f, 0.f};
#pragma unroll
      for (int q = 0; q < 8; ++q) {
        const float4 w = wp4[q];
        p01 = pkfma(v2f{rdlane(h1v, 4*q+0), rdlane(h1v, 4*q+1)},
                    v2f{w.x, w.y}, p01);
        p23 = pkfma(v2f{rdlane(h1v, 4*q+2), rdlane(h1v, 4*q+3)},
                    v2f{w.z, w.w}, p23);
      }
      const float pre   = bp + ((p01.x + p01.y) + (p23.x + p23.y));
      const float logit = 2.5f * ftanh(pre * 0.2f);   // TANH_CONST, 1/TEMP
      const float pert  = logit + gumbuf[t & 1][lane];

      // argmax via DPP-max + ballot (tie -> lowest index)
      const float M = wave_max64(pert);
      const unsigned long long msk = __ballot(pert == M);
      const int idxu = __ffsll((long long)msk) - 1;

      arch_lds[t] = (float)idxu;
      logit_prev = logit;
      idx_prev   = idxu;
      // hand next-step x row to wave0 (bit copy)
      xbuf[(t + 1) & 1][lane & 31] = embd_lds[idxu * H + (lane & 31)];
    }
    __syncthreads();   // E: xbuf(t+1), gum(t+1) visible to wave0
  }

  if (wid == 1) {
    // final deferred softmax (t = 127)
    const float e  = fexp(logit_prev);
    const float E  = wave_sum64(e);
    const float ES = wave_sum64(e * logit_prev);
    const float lse = flog(E);
    const float li  = rdlane(logit_prev, idx_prev);
    lp_sum  += li - lse;
    ent_sum += lse - ES / E;

    out[2 + lane]      = arch_lds[lane];
    out[2 + 64 + lane] = arch_lds[64 + lane];
    if (lane == 0) { out[0] = lp_sum; out[1] = ent_sum; }
  }
}

}  // namespace

extern "C" void kernel_launch(void* const* d_in, const int* in_sizes, int n_in,
                              void* d_out, int out_size, void* d_ws, size_t ws_size,
                              hipStream_t stream) {
  (void)in_sizes; (void)n_in; (void)d_ws; (void)ws_size; (void)out_size;
  const float* input_vars = (const float*)d_in[0];
  const float* W_ih0 = (const float*)d_in[1];
  const float* W_hh0 = (const float*)d_in[2];
  const float* b_ih0 = (const float*)d_in[3];
  const float* b_hh0 = (const float*)d_in[4];
  const float* W_ih1 = (const float*)d_in[5];
  const float* W_hh1 = (const float*)d_in[6];
  const float* b_ih1 = (const float*)d_in[7];
  const float* b_hh1 = (const float*)d_in[8];
  const float* embd  = (const float*)d_in[9];
  const float* W_pred = (const float*)d_in[10];
  const float* b_pred = (const float*)d_in[11];
  float* out = (float*)d_out;

  hipLaunchKernelGGL(ctrl_kernel, dim3(1), dim3(128), 0, stream,
                     input_vars, W_ih0, W_hh0, b_ih0, b_hh0,
                     W_ih1, W_hh1, b_ih1, b_hh1,
                     embd, W_pred, b_pred, out);
}

// Round 18
// 136.775 us; speedup vs baseline: 1.7351x; 1.0268x over previous
//
#include <hip/hip_runtime.h>
#include <stdint.h>

namespace {

typedef float v2f __attribute__((ext_vector_type(2)));
typedef int   v2i __attribute__((ext_vector_type(2)));

constexpr int H      = 32;    // LSTM_SIZE
constexpr int NEDGE  = 128;
constexpr float TINY   = 1.1754943508222875e-38f;  // finfo(f32).tiny
constexpr float L2E    = 1.4426950408889634f;      // log2(e)
constexpr float LN2    = 0.6931471805599453f;

__device__ __forceinline__ void tf_round(uint32_t& x0, uint32_t& x1, int r) {
  x0 += x1;
  x1 = (x1 << r) | (x1 >> (32 - r));
  x1 ^= x0;
}

// Threefry-2x32, 20 rounds — bit-exact JAX threefry2x32_p
__device__ __forceinline__ void tf2x32(uint32_t k0, uint32_t k1,
                                       uint32_t& x0, uint32_t& x1) {
  const uint32_t ks2 = k0 ^ k1 ^ 0x1BD11BDAu;
  x0 += k0; x1 += k1;
  tf_round(x0,x1,13); tf_round(x0,x1,15); tf_round(x0,x1,26); tf_round(x0,x1, 6);
  x0 += k1;  x1 += ks2 + 1u;
  tf_round(x0,x1,17); tf_round(x0,x1,29); tf_round(x0,x1,16); tf_round(x0,x1,24);
  x0 += ks2; x1 += k0 + 2u;
  tf_round(x0,x1,13); tf_round(x0,x1,15); tf_round(x0,x1,26); tf_round(x0,x1, 6);
  x0 += k0;  x1 += k1 + 3u;
  tf_round(x0,x1,17); tf_round(x0,x1,29); tf_round(x0,x1,16); tf_round(x0,x1,24);
  x0 += k1;  x1 += ks2 + 4u;
  tf_round(x0,x1,13); tf_round(x0,x1,15); tf_round(x0,x1,26); tf_round(x0,x1, 6);
  x0 += ks2; x1 += k0 + 5u;
}

// ---- native-instruction transcendentals
__device__ __forceinline__ float fexp(float x) {       // e^x
  return __builtin_amdgcn_exp2f(x * L2E);
}
__device__ __forceinline__ float flog(float x) {       // ln(x)
  return __builtin_amdgcn_logf(x) * LN2;
}
__device__ __forceinline__ float fsigmoid(float x) {   // 1/(1+e^-x)
  return __builtin_amdgcn_rcpf(1.0f + __builtin_amdgcn_exp2f(-x * L2E));
}
__device__ __forceinline__ float ftanh(float x) {
  const float ax = __builtin_fabsf(x);
  const float t  = __builtin_amdgcn_exp2f(ax * (-2.0f * L2E));  // e^(-2|x|)
  const float r  = (1.0f - t) * __builtin_amdgcn_rcpf(1.0f + t);
  return __builtin_copysignf(r, x);
}

__device__ __forceinline__ float rdlane(float v, int i) {
  return __int_as_float(__builtin_amdgcn_readlane(__float_as_int(v), i));
}

template <int CTRL>
__device__ __forceinline__ float dppf(float v) {
  return __int_as_float(__builtin_amdgcn_update_dpp(
      __float_as_int(v), __float_as_int(v), CTRL, 0xF, 0xF, false));
}

// 64-lane reductions: DPP butterfly within rows of 16, then 4 readlanes.
__device__ __forceinline__ float wave_sum64(float v) {
  v += dppf<0xB1>(v);
  v += dppf<0x4E>(v);
  v += dppf<0x141>(v);
  v += dppf<0x140>(v);
  return (rdlane(v, 15) + rdlane(v, 31)) + (rdlane(v, 47) + rdlane(v, 63));
}

__device__ __forceinline__ float wave_max64(float v) {
  v = fmaxf(v, dppf<0xB1>(v));
  v = fmaxf(v, dppf<0x4E>(v));
  v = fmaxf(v, dppf<0x141>(v));
  v = fmaxf(v, dppf<0x140>(v));
  return fmaxf(fmaxf(rdlane(v, 15), rdlane(v, 31)),
               fmaxf(rdlane(v, 47), rdlane(v, 63)));
}

__device__ __forceinline__ v2f pkfma(v2f a, v2f b, v2f c) {
  return __builtin_elementwise_fma(a, b, c);   // -> v_pk_fma_f32
}

// Cross-half swap (gfx950 VALU): r.x = g[lane&31] (i or g gate row),
// r.y = g[(lane&31)+32] (f or o gate row), identical in both halves.
__device__ __forceinline__ v2f permswap_pair(float g) {
  const v2i r = __builtin_amdgcn_permlane32_swap(
      __float_as_int(g), __float_as_int(g), false, false);
  return v2f{__int_as_float(r.x), __int_as_float(r.y)};
}

__global__ __launch_bounds__(192, 1)
void ctrl_kernel(const float* __restrict__ input_vars,
                 const float* __restrict__ W_ih0, const float* __restrict__ W_hh0,
                 const float* __restrict__ b_ih0, const float* __restrict__ b_hh0,
                 const float* __restrict__ W_ih1, const float* __restrict__ W_hh1,
                 const float* __restrict__ b_ih1, const float* __restrict__ b_hh1,
                 const float* __restrict__ embd,
                 const float* __restrict__ W_pred, const float* __restrict__ b_pred,
                 float* __restrict__ out) {
  const int tid  = threadIdx.x;  // wave0: LSTM0; wave1: LSTM1+sample; wave2: PRNG
  const int lane = tid & 63;
  const int wid  = tid >> 6;
  const int rB   = lane + 64;

  __shared__ float4 Wh[2][8][128];                 // W_hh0, W_hh1 (32 KiB)
  __shared__ __align__(16) float embd_lds[64 * H]; // 8 KiB
  __shared__ __align__(16) float h0buf[2][H];      // w0 -> w1, dbuf by t&1
  __shared__ __align__(16) float gumbuf[4][64];    // w2 -> w1, 4-deep (t+2 ahead)
  __shared__ __align__(16) float xbuf[2][H];       // w1 -> w0, dbuf by t&1
  __shared__ __align__(16) float arch_lds[NEDGE];

  // waves 0/1 stage weights+embd; wave2 runs the PRNG prologue concurrently
  if (wid < 2) {
#define STAGE(MAT, SRC)                                                    \
  _Pragma("unroll")                                                        \
  for (int j = 0; j < 8; ++j) {                                            \
    const int i = tid + 128 * j;                                           \
    const int k4 = i & 7, row = i >> 3;                                    \
    Wh[MAT][k4][row] = reinterpret_cast<const float4*>(SRC)[row * 8 + k4]; \
  }
    STAGE(0, W_hh0)
    STAGE(1, W_hh1)
#undef STAGE
#pragma unroll
    for (int j = 0; j < 4; ++j)
      reinterpret_cast<float4*>(embd_lds)[tid + 128 * j] =
          reinterpret_cast<const float4*>(embd)[tid + 128 * j];
    if (tid < 8)
      reinterpret_cast<float4*>(&xbuf[0][0])[tid] =
          reinterpret_cast<const float4*>(input_vars)[tid];  // x(0)
  }

  // Chain-leg input weights in REGISTERS: wave0 = W_ih0 rows, wave1 = W_ih1.
  const float* WX = (wid == 1) ? W_ih1 : W_ih0;
  float4 wxA[8], wxB[8];
#pragma unroll
  for (int q = 0; q < 8; ++q) {
    wxA[q] = reinterpret_cast<const float4*>(WX + lane * H)[q];
    wxB[q] = reinterpret_cast<const float4*>(WX + rB * H)[q];
  }
  const float bsum0A = b_ih0[lane] + b_hh0[lane];
  const float bsum0B = b_ih0[rB]   + b_hh0[rB];
  const float bsum1A = b_ih1[lane] + b_hh1[lane];
  const float bsum1B = b_ih1[rB]   + b_hh1[rB];
  const float bp = b_pred[lane];
  float4 wp4[8];
#pragma unroll
  for (int q = 0; q < 8; ++q)
    wp4[q] = reinterpret_cast<const float4*>(W_pred + lane * H)[q];

  float c0 = 0.f, h0v = 0.f;           // wave0 LSTM0 state
  float c1 = 0.f, h1v = 0.f;           // wave1 LSTM1 state
  v2f hoA01={0.f,0.f}, hoA23={0.f,0.f}, hoB01={0.f,0.f}, hoB23={0.f,0.f};
  uint32_t k0 = 0u, k1 = 42u;          // key chain (wave2)
  uint32_t s0c = 0u, s1c = 0u;         // subkey carried phase1 -> phase2
  float lp_sum = 0.f, ent_sum = 0.f;   // wave1
  float logit_prev = 0.f;
  int   idx_prev = 0;

  if (wid == 2) {
    // PRNG prologue: gum(0), gum(1) — exact same cipher sequence as R15
#pragma unroll 1
    for (int p = 0; p < 2; ++p) {
      uint32_t r0 = 0u, r1 = (uint32_t)(lane & 1);
      tf2x32(k0, k1, r0, r1);
      const uint32_t n0 = (uint32_t)__builtin_amdgcn_readlane((int)r0, 0);
      const uint32_t n1 = (uint32_t)__builtin_amdgcn_readlane((int)r1, 0);
      const uint32_t s0 = (uint32_t)__builtin_amdgcn_readlane((int)r0, 1);
      const uint32_t s1 = (uint32_t)__builtin_amdgcn_readlane((int)r1, 1);
      uint32_t x0 = 0u, x1 = (uint32_t)lane;
      tf2x32(s0, s1, x0, x1);
      const uint32_t bits = x0 ^ x1;
      k0 = n0; k1 = n1;
      float u = __uint_as_float(0x3f800000u | (bits >> 9)) - 1.0f;
      u = fmaxf(u + TINY, TINY);
      gumbuf[p][lane] = -flog(-flog(u));
    }
  }
  __syncthreads();

  for (int t = 0; t < NEDGE; ++t) {
    // wave1 LSTM1 accumulators (phase1 hoisted -> phase2 finish)
    v2f rA01={0.f,0.f}, rA23={0.f,0.f}, rB01={0.f,0.f}, rB23={0.f,0.f};

    // ======== phase1 ========
    if (wid == 0) {
      // finish LSTM0(t): x-dot (register weights, uniform xbuf) + hoisted h-dot
      v2f xA01={0.f,0.f}, xA23={0.f,0.f}, xB01={0.f,0.f}, xB23={0.f,0.f};
#pragma unroll
      for (int q = 0; q < 8; ++q) {
        const float4 x4 =
            *reinterpret_cast<const float4*>(&xbuf[t & 1][4 * q]);
        xA01 = pkfma(v2f{x4.x, x4.y}, v2f{wxA[q].x, wxA[q].y}, xA01);
        xA23 = pkfma(v2f{x4.z, x4.w}, v2f{wxA[q].z, wxA[q].w}, xA23);
        xB01 = pkfma(v2f{x4.x, x4.y}, v2f{wxB[q].x, wxB[q].y}, xB01);
        xB23 = pkfma(v2f{x4.z, x4.w}, v2f{wxB[q].z, wxB[q].w}, xB23);
      }
      const float gA = bsum0A + ((xA01.x + xA01.y) + (xA23.x + xA23.y))
                              + ((hoA01.x + hoA01.y) + (hoA23.x + hoA23.y));
      const float gB = bsum0B + ((xB01.x + xB01.y) + (xB23.x + xB23.y))
                              + ((hoB01.x + hoB01.y) + (hoB23.x + hoB23.y));
      const v2f gif = permswap_pair(gA);   // .x = i, .y = f
      const v2f ggo = permswap_pair(gB);   // .x = g, .y = o
      c0 = fsigmoid(gif.y) * c0 + fsigmoid(gif.x) * ftanh(ggo.x);
      h0v = fsigmoid(ggo.y) * ftanh(c0);
      h0buf[t & 1][lane & 31] = h0v;       // 2 lanes/addr same data: free
    } else if (wid == 1) {
      // hoisted LSTM1 h1(t-1)-dot via rdlane pairs against LDS W_hh1
#pragma unroll
      for (int q = 0; q < 8; ++q) {
        const float4 wA = Wh[1][q][lane];
        const float4 wB = Wh[1][q][rB];
        const v2f h01 = {rdlane(h1v, 4*q+0), rdlane(h1v, 4*q+1)};
        const v2f h23 = {rdlane(h1v, 4*q+2), rdlane(h1v, 4*q+3)};
        rA01 = pkfma(h01, v2f{wA.x, wA.y}, rA01);
        rA23 = pkfma(h23, v2f{wA.z, wA.w}, rA23);
        rB01 = pkfma(h01, v2f{wB.x, wB.y}, rB01);
        rB23 = pkfma(h23, v2f{wB.z, wB.w}, rB23);
      }
      if (t > 0) {
        // deferred softmax stats for step t-1
        const float e  = fexp(logit_prev);
        const float E  = wave_sum64(e);
        const float ES = wave_sum64(e * logit_prev);
        const float lse = flog(E);
        const float li  = rdlane(logit_prev, idx_prev);
        lp_sum  += li - lse;
        ent_sum += lse - ES / E;
      }
    } else {
      // cipher1 for step t+2: key_{t+2} -> (key_{t+3}, sub_{t+2})
      uint32_t r0 = 0u, r1 = (uint32_t)(lane & 1);
      tf2x32(k0, k1, r0, r1);
      k0  = (uint32_t)__builtin_amdgcn_readlane((int)r0, 0);
      k1  = (uint32_t)__builtin_amdgcn_readlane((int)r1, 0);
      s0c = (uint32_t)__builtin_amdgcn_readlane((int)r0, 1);
      s1c = (uint32_t)__builtin_amdgcn_readlane((int)r1, 1);
    }
    __syncthreads();   // M: h0(t) visible to wave1

    // ======== phase2 ========
    if (wid == 0) {
      // hoisted LSTM0 h0(t)-dot for step t+1 (own registers, LDS W_hh0)
      hoA01 = v2f{0.f,0.f}; hoA23 = v2f{0.f,0.f};
      hoB01 = v2f{0.f,0.f}; hoB23 = v2f{0.f,0.f};
#pragma unroll
      for (int q = 0; q < 8; ++q) {
        const float4 wA = Wh[0][q][lane];
        const float4 wB = Wh[0][q][rB];
        const v2f h01 = {rdlane(h0v, 4*q+0), rdlane(h0v, 4*q+1)};
        const v2f h23 = {rdlane(h0v, 4*q+2), rdlane(h0v, 4*q+3)};
        hoA01 = pkfma(h01, v2f{wA.x, wA.y}, hoA01);
        hoA23 = pkfma(h23, v2f{wA.z, wA.w}, hoA23);
        hoB01 = pkfma(h01, v2f{wB.x, wB.y}, hoB01);
        hoB23 = pkfma(h23, v2f{wB.z, wB.w}, hoB23);
      }
    } else if (wid == 1) {
      // finish LSTM1(t): x-part = h0(t) uniform reads x register W_ih1 rows
#pragma unroll
      for (int q = 0; q < 8; ++q) {
        const float4 h4 =
            *reinterpret_cast<const float4*>(&h0buf[t & 1][4 * q]);
        rA01 = pkfma(v2f{h4.x, h4.y}, v2f{wxA[q].x, wxA[q].y}, rA01);
        rA23 = pkfma(v2f{h4.z, h4.w}, v2f{wxA[q].z, wxA[q].w}, rA23);
        rB01 = pkfma(v2f{h4.x, h4.y}, v2f{wxB[q].x, wxB[q].y}, rB01);
        rB23 = pkfma(v2f{h4.z, h4.w}, v2f{wxB[q].z, wxB[q].w}, rB23);
      }
      const float gA1 = bsum1A + ((rA01.x + rA01.y) + (rA23.x + rA23.y));
      const float gB1 = bsum1B + ((rB01.x + rB01.y) + (rB23.x + rB23.y));
      const v2f gif1 = permswap_pair(gA1);
      const v2f ggo1 = permswap_pair(gB1);
      c1  = fsigmoid(gif1.y) * c1 + fsigmoid(gif1.x) * ftanh(ggo1.x);
      h1v = fsigmoid(ggo1.y) * ftanh(c1);

      // logits (lane = op index), pkfma-packed
      v2f p01 = {0.f, 0.f}, p23 = {0.f, 0.f};
#pragma unroll
      for (int q = 0; q < 8; ++q) {
        const float4 w = wp4[q];
        p01 = pkfma(v2f{rdlane(h1v, 4*q+0), rdlane(h1v, 4*q+1)},
                    v2f{w.x, w.y}, p01);
        p23 = pkfma(v2f{rdlane(h1v, 4*q+2), rdlane(h1v, 4*q+3)},
                    v2f{w.z, w.w}, p23);
      }
      const float pre   = bp + ((p01.x + p01.y) + (p23.x + p23.y));
      const float logit = 2.5f * ftanh(pre * 0.2f);   // TANH_CONST, 1/TEMP
      const float pert  = logit + gumbuf[t & 3][lane];

      // argmax via DPP-max + ballot (tie -> lowest index)
      const float M = wave_max64(pert);
      const unsigned long long msk = __ballot(pert == M);
      const int idxu = __ffsll((long long)msk) - 1;

      arch_lds[t] = (float)idxu;
      logit_prev = logit;
      idx_prev   = idxu;
      // hand next-step x row to wave0 (bit copy)
      xbuf[(t + 1) & 1][lane & 31] = embd_lds[idxu * H + (lane & 31)];
    } else {
      // cipher2(sub_{t+2}) -> gum(t+2); write is 2 steps ahead of the reader
      uint32_t x0 = 0u, x1 = (uint32_t)lane;
      tf2x32(s0c, s1c, x0, x1);
      const uint32_t bits = x0 ^ x1;
      float u = __uint_as_float(0x3f800000u | (bits >> 9)) - 1.0f;
      u = fmaxf(u + TINY, TINY);
      gumbuf[(t + 2) & 3][lane] = -flog(-flog(u));
    }
    __syncthreads();   // E: xbuf(t+1), gum handoffs visible
  }

  if (wid == 1) {
    // final deferred softmax (t = 127)
    const float e  = fexp(logit_prev);
    const float E  = wave_sum64(e);
    const float ES = wave_sum64(e * logit_prev);
    const float lse = flog(E);
    const float li  = rdlane(logit_prev, idx_prev);
    lp_sum  += li - lse;
    ent_sum += lse - ES / E;

    out[2 + lane]      = arch_lds[lane];
    out[2 + 64 + lane] = arch_lds[64 + lane];
    if (lane == 0) { out[0] = lp_sum; out[1] = ent_sum; }
  }
}

}  // namespace

extern "C" void kernel_launch(void* const* d_in, const int* in_sizes, int n_in,
                              void* d_out, int out_size, void* d_ws, size_t ws_size,
                              hipStream_t stream) {
  (void)in_sizes; (void)n_in; (void)d_ws; (void)ws_size; (void)out_size;
  const float* input_vars = (const float*)d_in[0];
  const float* W_ih0 = (const float*)d_in[1];
  const float* W_hh0 = (const float*)d_in[2];
  const float* b_ih0 = (const float*)d_in[3];
  const float* b_hh0 = (const float*)d_in[4];
  const float* W_ih1 = (const float*)d_in[5];
  const float* W_hh1 = (const float*)d_in[6];
  const float* b_ih1 = (const float*)d_in[7];
  const float* b_hh1 = (const float*)d_in[8];
  const float* embd  = (const float*)d_in[9];
  const float* W_pred = (const float*)d_in[10];
  const float* b_pred = (const float*)d_in[11];
  float* out = (float*)d_out;

  hipLaunchKernelGGL(ctrl_kernel, dim3(1), dim3(192), 0, stream,
                     input_vars, W_ih0, W_hh0, b_ih0, b_hh0,
                     W_ih1, W_hh1, b_ih1, b_hh1,
                     embd, W_pred, b_pred, out);
}